// Round 10
// baseline (135.601 us; speedup 1.0000x reference)
//
#include <hip/hip_runtime.h>
#include <math.h>

// Problem constants (from reference)
#define B      512
#define DF     2048
#define DA     312
#define NTHR   320        // 5 waves; threads 0..311 each own one output column
#define RT     8          // rows per block tile (R6 proven shape)
#define KSPLIT 16         // k-split factor (grid.y) — R6 proven value
#define NRG    (B / RT)   // 64 row groups
#define TK     16         // k-rows of W per LDS stage (19968 B per buffer)

// ---------------------------------------------------------------------------
// Wave (64-lane) reduction helpers
// ---------------------------------------------------------------------------
__device__ __forceinline__ float wave_max_f(float v) {
  #pragma unroll
  for (int off = 32; off >= 1; off >>= 1)
    v = fmaxf(v, __shfl_down(v, off));
  return v;
}

__device__ __forceinline__ double wave_sum_d(double v) {
  #pragma unroll
  for (int off = 32; off >= 1; off >>= 1)
    v += __shfl_down(v, off);
  return v;
}

// Tiny device-coherent accessors (rounds 1/3/4 lesson: ANY intra-kernel
// cross-block mechanism costs ~6 us/MB -> use ONLY for KB-scale data).
__device__ __forceinline__ void dev_store_d(double* p, double v) {
  __hip_atomic_store(p, v, __ATOMIC_RELAXED, __HIP_MEMORY_SCOPE_AGENT);
}
__device__ __forceinline__ double dev_load_d(const double* p) {
  return __hip_atomic_load(p, __ATOMIC_RELAXED, __HIP_MEMORY_SCOPE_AGENT);
}
__device__ __forceinline__ void dev_store_i(int* p, int v) {
  __hip_atomic_store(p, v, __ATOMIC_RELAXED, __HIP_MEMORY_SCOPE_AGENT);
}
__device__ __forceinline__ int dev_load_i(const int* p) {
  return __hip_atomic_load(p, __ATOMIC_RELAXED, __HIP_MEMORY_SCOPE_AGENT);
}

// ---------------------------------------------------------------------------
// K1 (R10): split-K GEMM with block-cooperative double-buffered LDS staging
// of W. Theory: R6's per-thread strided W loads expose L2 latency (128-cyc
// FMA cover < 200-450-cyc load latency per octet) and neither occupancy (R9)
// nor register prefetch depth (R2) fixed it. Here W k-rows (contiguous in
// memory) are staged as bulk float4 copies a full chunk ahead (T14 issue-
// early/write-late, reg-staged), and FMAs read W from LDS (ds_read_b32,
// lane c -> consecutive dwords, conflict-free, ~6 cyc).
// UNCHANGED vs R6 (bitwise): x scalar-load path (block-uniform addressing ->
// s_load; R8 lesson), FMA order (k-octet -> r -> j), partial layout, ticket.
// Occupancy: LDS 39936 B/block -> 4 blocks/CU x 5 waves = 20 waves/CU (= R6).
// ---------------------------------------------------------------------------
template <int KC>
__global__ __launch_bounds__(NTHR, 5) void gemm_partial_kernel(
    const float* __restrict__ x_f, const float* __restrict__ W,
    float* __restrict__ part, int* ticket) {
  constexpr int NCH = KC / TK;              // 8 chunks
  constexpr int NF4 = TK * DA / 4;          // 1248 float4 units per chunk
  __shared__ __align__(16) float wbuf[2][TK * DA];

  const int tid  = threadIdx.x;
  const int c    = tid;
  const int rg   = blockIdx.x;
  const int ks   = blockIdx.y;
  const int row0 = rg * RT;
  const int k0   = ks * KC;
  const int ksplit = DF / KC;
  const bool active = (c < DA);

  if (blockIdx.x == 0 && blockIdx.y == 0 && tid == 0)
    *ticket = 0;   // visible to K2' via end-of-dispatch release

  const float* wsrc = W + (size_t)k0 * DA;          // chunk ch at +ch*TK*DA
  const float* xp   = x_f + (size_t)row0 * DF + k0; // block-uniform

  float acc[RT];
  #pragma unroll
  for (int r = 0; r < RT; ++r) acc[r] = 0.f;

  float4 ld[4];                                     // staging registers

  // ---- prologue: stage chunk 0 ----
  {
    const float4* s = (const float4*)wsrc;
    #pragma unroll
    for (int rd = 0; rd < 4; ++rd) {
      const int idx = rd * NTHR + tid;
      if (idx < NF4) ld[rd] = s[idx];
    }
    float4* d = (float4*)wbuf[0];
    #pragma unroll
    for (int rd = 0; rd < 4; ++rd) {
      const int idx = rd * NTHR + tid;
      if (idx < NF4) d[idx] = ld[rd];
    }
  }
  __syncthreads();

  // ---- main loop: {issue next-chunk loads | compute cur | write next} ----
  for (int ch = 0; ch < NCH; ++ch) {
    const int cur = ch & 1;

    if (ch + 1 < NCH) {                     // T14: issue loads EARLY
      const float4* s = (const float4*)(wsrc + (size_t)(ch + 1) * TK * DA);
      #pragma unroll
      for (int rd = 0; rd < 4; ++rd) {
        const int idx = rd * NTHR + tid;
        if (idx < NF4) ld[rd] = s[idx];
      }
    }

    if (active) {                           // compute on wbuf[cur]
      #pragma unroll
      for (int o = 0; o < TK / 8; ++o) {    // 2 octets, same k order as R6
        const int kk = ch * TK + o * 8;
        float wv[8];
        #pragma unroll
        for (int j = 0; j < 8; ++j) wv[j] = wbuf[cur][(o * 8 + j) * DA + c];
        #pragma unroll
        for (int r = 0; r < RT; ++r) {
          const float* xr = xp + (size_t)r * DF + kk;  // uniform -> s_load
          #pragma unroll
          for (int j = 0; j < 8; ++j) acc[r] = fmaf(xr[j], wv[j], acc[r]);
        }
      }
    }

    if (ch + 1 < NCH) {                     // T14: write LATE (latency hidden)
      float4* d = (float4*)wbuf[(ch + 1) & 1];
      #pragma unroll
      for (int rd = 0; rd < 4; ++rd) {
        const int idx = rd * NTHR + tid;
        if (idx < NF4) d[idx] = ld[rd];
      }
    }
    __syncthreads();                        // one barrier per chunk
  }

  if (active) {
    float* pp = part + ((size_t)(rg * ksplit + ks) * RT) * DA + c;
    #pragma unroll
    for (int r = 0; r < RT; ++r) pp[(size_t)r * DA] = acc[r];
  }
}

// ---------------------------------------------------------------------------
// K2': per-row rowstats (proven math: bias + partials p=0..KS-1, block max,
// double exp/sum, S = sum(pre) - DA*(max + log sum exp)) FUSED with the
// pair reduction via the rank identity:
//   sum_{i<j,same}(S_j - S_i) = sum_i (2*rank_i - m_i + 1) * S_i
//   count                     = sum_i rank_i
// Each block publishes ONE double (coef*S) + ONE int (rank) = 12 B of scoped
// traffic; ticket winner (last of 512) sums them. No spin-waits.
// ---------------------------------------------------------------------------
template <int KS>
__global__ __launch_bounds__(NTHR) void rowstats_pair_kernel(
    const float* __restrict__ part, const float* __restrict__ b,
    const int* __restrict__ labels,
    double* T, int* RK, int* ticket, float* __restrict__ out) {
  __shared__ float  red_f[8];
  __shared__ double red_d[16];
  __shared__ int    red_i[16];
  __shared__ float  bcast_max;
  __shared__ int    ticket_sh;
  __shared__ int    Lsh[B];

  const int tid  = threadIdx.x;
  const int wid  = tid >> 6;
  const int lane = tid & 63;
  const int row  = blockIdx.x;
  const int rg   = row / RT;
  const int r    = row & (RT - 1);

  // labels -> LDS (for rank/m scan)
  for (int i = tid; i < B; i += NTHR) Lsh[i] = labels[i];

  // issue partial loads early (independent of LDS)
  float v = -INFINITY;
  float ps[KS];
  const bool active = (tid < DA);
  if (active) {
    const float* pb = part + ((size_t)(rg * KS) * RT + r) * DA + tid;
    #pragma unroll
    for (int p = 0; p < KS; ++p) ps[p] = pb[(size_t)p * RT * DA];
  }

  __syncthreads();                      // Lsh ready

  // rank/m for this row: each thread scans a stride of labels
  const int myl = Lsh[row];
  int c_less = 0, c_all = 0;
  for (int j = tid; j < B; j += NTHR) {
    const int same = (Lsh[j] == myl) ? 1 : 0;
    c_all += same;
    if (j < row) c_less += same;
  }
  #pragma unroll
  for (int off = 32; off >= 1; off >>= 1) {
    c_less += __shfl_down(c_less, off);
    c_all  += __shfl_down(c_all,  off);
  }
  if (lane == 0) { red_i[wid] = c_less; red_i[8 + wid] = c_all; }

  // ---- rowstats (proven math, fixed order p=0..KS-1) ----
  if (active) {
    float s = b[tid];
    #pragma unroll
    for (int p = 0; p < KS; ++p) s += ps[p];
    v = s;
  }

  float m = wave_max_f(v);
  if (lane == 0) red_f[wid] = m;
  __syncthreads();                      // also covers red_i before tid0 read
  if (tid == 0) {
    float mm = red_f[0];
    #pragma unroll
    for (int w = 1; w < NTHR / 64; ++w) mm = fmaxf(mm, red_f[w]);
    bcast_max = mm;
  }
  __syncthreads();
  const float rowmax = bcast_max;

  double e  = active ? exp((double)v - (double)rowmax) : 0.0;
  double sp = active ? (double)v : 0.0;
  double es = wave_sum_d(e);
  double ss = wave_sum_d(sp);
  if (lane == 0) { red_d[wid] = es; red_d[8 + wid] = ss; }
  __syncthreads();
  if (tid == 0) {
    double esum = 0.0, ssum = 0.0;
    int rank = 0, mcnt = 0;
    #pragma unroll
    for (int w = 0; w < NTHR / 64; ++w) {
      esum += red_d[w]; ssum += red_d[8 + w];
      rank += red_i[w]; mcnt += red_i[8 + w];
    }
    const double S    = ssum - (double)DA * ((double)rowmax + log(esum));
    const double coef = (double)(2 * rank - mcnt + 1);
    dev_store_d(&T[row], coef * S);     // 8 B scoped publish
    dev_store_i(&RK[row], rank);        // 4 B scoped publish
  }

  asm volatile("s_waitcnt vmcnt(0)" ::: "memory");   // publishes at LLC
  __syncthreads();
  if (tid == 0)
    ticket_sh = __hip_atomic_fetch_add(ticket, 1, __ATOMIC_RELAXED,
                                       __HIP_MEMORY_SCOPE_AGENT);
  __syncthreads();
  if (ticket_sh != B - 1) return;       // not the last row block
  asm volatile("" ::: "memory");        // don't hoist loads above ticket

  // ---- tail (winner block): sum 512 doubles + 512 ints, write loss ----
  double tloc = 0.0;
  int    rloc = 0;
  for (int i = tid; i < B; i += NTHR) { // fixed per-thread order: i, i+320
    tloc += dev_load_d(&T[i]);
    rloc += dev_load_i(&RK[i]);
  }
  #pragma unroll
  for (int off = 32; off >= 1; off >>= 1) {
    tloc += __shfl_down(tloc, off);
    rloc += __shfl_down(rloc, off);
  }
  if (lane == 0) { red_d[wid] = tloc; red_i[wid] = rloc; }
  __syncthreads();
  if (tid == 0) {
    double ts = 0.0; int rs = 0;
    #pragma unroll
    for (int w = 0; w < NTHR / 64; ++w) { ts += red_d[w]; rs += red_i[w]; }
    out[0] = (float)((rs > 0) ? ts / (double)rs : ts);
  }
}

// ---------------------------------------------------------------------------
// Fallback 3-kernel path (proven, for tiny workspace): ksplit=2.
// ---------------------------------------------------------------------------
template <int KCF>
__global__ __launch_bounds__(NTHR) void gemm_partial_fb(
    const float* __restrict__ x_f, const float* __restrict__ W,
    float* __restrict__ part) {
  const int c = threadIdx.x, rg = blockIdx.x, ks = blockIdx.y;
  const int row0 = rg * RT, k0 = ks * KCF, ksplit = DF / KCF;
  if (c >= DA) return;
  float acc[RT];
  #pragma unroll
  for (int r = 0; r < RT; ++r) acc[r] = 0.f;
  const float* Wp = W + (size_t)k0 * DA + c;
  const float* xp = x_f + (size_t)row0 * DF + k0;
  for (int k = 0; k < KCF; k += 8) {
    float w[8];
    #pragma unroll
    for (int j = 0; j < 8; ++j) w[j] = Wp[(size_t)(k + j) * DA];
    #pragma unroll
    for (int r = 0; r < RT; ++r) {
      const float* xr = xp + (size_t)r * DF + k;
      #pragma unroll
      for (int j = 0; j < 8; ++j) acc[r] = fmaf(xr[j], w[j], acc[r]);
    }
  }
  float* pp = part + ((size_t)(rg * ksplit + ks) * RT) * DA + c;
  #pragma unroll
  for (int r = 0; r < RT; ++r) pp[(size_t)r * DA] = acc[r];
}

template <int KS>
__global__ __launch_bounds__(NTHR) void row_stats_fb(
    const float* __restrict__ part, const float* __restrict__ b,
    double* __restrict__ S) {
  __shared__ float  red_f[8];
  __shared__ double red_d[16];
  __shared__ float  bcast_max;
  const int tid = threadIdx.x, wid = tid >> 6, lane = tid & 63;
  const int row = blockIdx.x, rg = row / RT, r = row & (RT - 1);
  float v = -INFINITY;
  if (tid < DA) {
    const float* pb = part + ((size_t)(rg * KS) * RT + r) * DA + tid;
    float ps[KS];
    #pragma unroll
    for (int p = 0; p < KS; ++p) ps[p] = pb[(size_t)p * RT * DA];
    float sv = b[tid];
    #pragma unroll
    for (int p = 0; p < KS; ++p) sv += ps[p];
    v = sv;
  }
  float m = wave_max_f(v);
  if (lane == 0) red_f[wid] = m;
  __syncthreads();
  if (tid == 0) {
    float mm = red_f[0];
    #pragma unroll
    for (int w = 1; w < NTHR / 64; ++w) mm = fmaxf(mm, red_f[w]);
    bcast_max = mm;
  }
  __syncthreads();
  const float rowmax = bcast_max;
  double e  = (tid < DA) ? exp((double)v - (double)rowmax) : 0.0;
  double sp = (tid < DA) ? (double)v : 0.0;
  double es = wave_sum_d(e);
  double ss = wave_sum_d(sp);
  if (lane == 0) { red_d[wid] = es; red_d[8 + wid] = ss; }
  __syncthreads();
  if (tid == 0) {
    double esum = 0.0, ssum = 0.0;
    #pragma unroll
    for (int w = 0; w < NTHR / 64; ++w) { esum += red_d[w]; ssum += red_d[8 + w]; }
    S[row] = ssum - (double)DA * ((double)rowmax + log(esum));
  }
}

__global__ __launch_bounds__(1024) void pair_reduce_fb(
    const double* __restrict__ S, const int* __restrict__ labels,
    float* __restrict__ out) {
  __shared__ double    Ss[B];
  __shared__ int       Ls[B];
  __shared__ double    red_d[16];
  __shared__ long long red_i[16];
  const int tid = threadIdx.x;
  if (tid < B) { Ss[tid] = S[tid]; Ls[tid] = labels[tid]; }
  __syncthreads();
  double lsum = 0.0;
  long long lcnt = 0;
  for (int p = tid; p < B * B; p += 1024) {
    int i = p >> 9, j = p & (B - 1);
    if (j > i && Ls[i] == Ls[j]) { lsum += Ss[j] - Ss[i]; lcnt++; }
  }
  #pragma unroll
  for (int off = 32; off >= 1; off >>= 1) {
    lsum += __shfl_down(lsum, off);
    lcnt += __shfl_down(lcnt, off);
  }
  const int wid = tid >> 6, lane = tid & 63;
  if (lane == 0) { red_d[wid] = lsum; red_i[wid] = lcnt; }
  __syncthreads();
  if (tid == 0) {
    double s = 0.0; long long c = 0;
    #pragma unroll
    for (int w = 0; w < 16; ++w) { s += red_d[w]; c += red_i[w]; }
    out[0] = (float)((c > 0) ? s / (double)c : s);
  }
}

// ---------------------------------------------------------------------------
extern "C" void kernel_launch(void* const* d_in, const int* in_sizes, int n_in,
                              void* d_out, int out_size, void* d_ws, size_t ws_size,
                              hipStream_t stream) {
  const float* x_f    = (const float*)d_in[0];   // [B, DF]
  const float* W      = (const float*)d_in[1];   // [DF, DA]
  const float* b      = (const float*)d_in[2];   // [DA]
  // d_in[3] = seen_att: cancels exactly for same-label pairs (unused)
  const int*   labels = (const int*)d_in[4];     // [B]

  // ws layout: [ticket @0][T: 512 doubles @4096][RK: 512 ints @8192]
  //            [part @16384: KSPLIT*B*DA floats (~10.2 MB)]
  const size_t need = 16384 + (size_t)KSPLIT * B * DA * 4;
  if (ws_size >= need) {
    int*    ticket = (int*)d_ws;
    double* T      = (double*)((char*)d_ws + 4096);
    int*    RK     = (int*)((char*)d_ws + 8192);
    float*  part   = (float*)((char*)d_ws + 16384);
    dim3 g1(NRG, KSPLIT);                         // 64 x 16 = 1024 blocks
    gemm_partial_kernel<DF / KSPLIT><<<g1, NTHR, 0, stream>>>(x_f, W, part,
                                                              ticket);
    rowstats_pair_kernel<KSPLIT><<<B, NTHR, 0, stream>>>(
        part, b, labels, T, RK, ticket, (float*)d_out);
  } else {                                       // tiny-ws fallback (proven)
    double* S    = (double*)d_ws;
    float*  part = (float*)((char*)d_ws + 4096);
    dim3 g1(B / RT, 2);
    gemm_partial_fb<DF / 2><<<g1, NTHR, 0, stream>>>(x_f, W, part);
    row_stats_fb<2><<<B, NTHR, 0, stream>>>(part, b, S);
    pair_reduce_fb<<<1, 1024, 0, stream>>>(S, labels, (float*)d_out);
  }
}

// Round 11
// 93.445 us; speedup vs baseline: 1.4511x; 1.4511x over previous
//
#include <hip/hip_runtime.h>
#include <math.h>

// Problem constants (from reference)
#define B      512
#define DF     2048
#define DA     312
#define NTHR   320        // 5 waves; threads 0..311 each own one output column
#define RT     8          // rows per block tile in the GEMM
#define KSPLIT 16         // k-split factor (grid.y)
#define NRG    (B / RT)   // 64 row groups

// ---------------------------------------------------------------------------
// Wave (64-lane) reduction helpers
// ---------------------------------------------------------------------------
__device__ __forceinline__ float wave_max_f(float v) {
  #pragma unroll
  for (int off = 32; off >= 1; off >>= 1)
    v = fmaxf(v, __shfl_down(v, off));
  return v;
}

__device__ __forceinline__ double wave_sum_d(double v) {
  #pragma unroll
  for (int off = 32; off >= 1; off >>= 1)
    v += __shfl_down(v, off);
  return v;
}

// Tiny device-coherent accessors (rounds 1/3/4 lesson: ANY intra-kernel
// cross-block mechanism costs ~6 us/MB -> use ONLY for KB-scale data).
__device__ __forceinline__ void dev_store_d(double* p, double v) {
  __hip_atomic_store(p, v, __ATOMIC_RELAXED, __HIP_MEMORY_SCOPE_AGENT);
}
__device__ __forceinline__ double dev_load_d(const double* p) {
  return __hip_atomic_load(p, __ATOMIC_RELAXED, __HIP_MEMORY_SCOPE_AGENT);
}
__device__ __forceinline__ void dev_store_i(int* p, int v) {
  __hip_atomic_store(p, v, __ATOMIC_RELAXED, __HIP_MEMORY_SCOPE_AGENT);
}
__device__ __forceinline__ int dev_load_i(const int* p) {
  return __hip_atomic_load(p, __ATOMIC_RELAXED, __HIP_MEMORY_SCOPE_AGENT);
}

// ---------------------------------------------------------------------------
// K1: split-K GEMM partials, NO LDS (R6 proven codegen — DO NOT PERTURB).
// Attack ledger (all failed): R2 unroll/prefetch null; R7 RT=16 regress
// (occupancy); R8 640-thr W-reuse regress (broke s_load uniformity);
// R9 KSPLIT=32 occupancy+50% exactly null; R10 LDS staging regress (scratch
// spill, WRITE_SIZE 10->78MB). Thread c owns one output column: W reads
// lane-contiguous coalesced; x reads block-uniform -> s_load.
// Also zeroes the K2' ticket (kernel-boundary coherence).
// ---------------------------------------------------------------------------
template <int KC>
__global__ __launch_bounds__(NTHR) void gemm_partial_kernel(
    const float* __restrict__ x_f, const float* __restrict__ W,
    float* __restrict__ part, int* ticket) {
  const int c    = threadIdx.x;
  const int rg   = blockIdx.x;
  const int ks   = blockIdx.y;
  const int row0 = rg * RT;
  const int k0   = ks * KC;
  const int ksplit = DF / KC;

  if (blockIdx.x == 0 && blockIdx.y == 0 && threadIdx.x == 0)
    *ticket = 0;   // visible to K2' via end-of-dispatch release

  if (c >= DA) return;

  float acc[RT];
  #pragma unroll
  for (int r = 0; r < RT; ++r) acc[r] = 0.f;

  const float* Wp = W + (size_t)k0 * DA + c;
  const float* xp = x_f + (size_t)row0 * DF + k0;

  float wc[8];
  #pragma unroll
  for (int j = 0; j < 8; ++j) wc[j] = Wp[(size_t)j * DA];

  #pragma unroll
  for (int k = 0; k < KC; k += 8) {
    float wn[8];
    if (k + 8 < KC) {                    // prefetch next octet of W
      #pragma unroll
      for (int j = 0; j < 8; ++j) wn[j] = Wp[(size_t)(k + 8 + j) * DA];
    }
    #pragma unroll
    for (int r = 0; r < RT; ++r) {
      const float* xr = xp + (size_t)r * DF + k;  // wave-uniform -> s_load
      #pragma unroll
      for (int j = 0; j < 8; ++j) acc[r] = fmaf(xr[j], wc[j], acc[r]);
    }
    if (k + 8 < KC) {
      #pragma unroll
      for (int j = 0; j < 8; ++j) wc[j] = wn[j];
    }
  }

  float* pp = part + ((size_t)(rg * ksplit + ks) * RT) * DA + c;
  #pragma unroll
  for (int r = 0; r < RT; ++r) pp[(size_t)r * DA] = acc[r];
}

// ---------------------------------------------------------------------------
// K2': per-row rowstats (proven math: bias + partials p=0..KS-1, block max,
// double exp/sum, S = sum(pre) - DA*(max + log sum exp)) FUSED with the
// pair reduction via the rank identity:
//   sum_{i<j,same}(S_j - S_i) = sum_i (2*rank_i - m_i + 1) * S_i
//   count                     = sum_i rank_i
// Each block publishes ONE double (coef*S) + ONE int (rank) = 12 B of scoped
// traffic; ticket winner (last of 512) sums them. No spin-waits.
// ---------------------------------------------------------------------------
template <int KS>
__global__ __launch_bounds__(NTHR) void rowstats_pair_kernel(
    const float* __restrict__ part, const float* __restrict__ b,
    const int* __restrict__ labels,
    double* T, int* RK, int* ticket, float* __restrict__ out) {
  __shared__ float  red_f[8];
  __shared__ double red_d[16];
  __shared__ int    red_i[16];
  __shared__ float  bcast_max;
  __shared__ int    ticket_sh;
  __shared__ int    Lsh[B];

  const int tid  = threadIdx.x;
  const int wid  = tid >> 6;
  const int lane = tid & 63;
  const int row  = blockIdx.x;
  const int rg   = row / RT;
  const int r    = row & (RT - 1);

  // labels -> LDS (for rank/m scan)
  for (int i = tid; i < B; i += NTHR) Lsh[i] = labels[i];

  // issue partial loads early (independent of LDS)
  float v = -INFINITY;
  float ps[KS];
  const bool active = (tid < DA);
  if (active) {
    const float* pb = part + ((size_t)(rg * KS) * RT + r) * DA + tid;
    #pragma unroll
    for (int p = 0; p < KS; ++p) ps[p] = pb[(size_t)p * RT * DA];
  }

  __syncthreads();                      // Lsh ready

  // rank/m for this row: each thread scans a stride of labels
  const int myl = Lsh[row];
  int c_less = 0, c_all = 0;
  for (int j = tid; j < B; j += NTHR) {
    const int same = (Lsh[j] == myl) ? 1 : 0;
    c_all += same;
    if (j < row) c_less += same;
  }
  #pragma unroll
  for (int off = 32; off >= 1; off >>= 1) {
    c_less += __shfl_down(c_less, off);
    c_all  += __shfl_down(c_all,  off);
  }
  if (lane == 0) { red_i[wid] = c_less; red_i[8 + wid] = c_all; }

  // ---- rowstats (proven math, fixed order p=0..KS-1) ----
  if (active) {
    float s = b[tid];
    #pragma unroll
    for (int p = 0; p < KS; ++p) s += ps[p];
    v = s;
  }

  float m = wave_max_f(v);
  if (lane == 0) red_f[wid] = m;
  __syncthreads();                      // also covers red_i before tid0 read
  if (tid == 0) {
    float mm = red_f[0];
    #pragma unroll
    for (int w = 1; w < NTHR / 64; ++w) mm = fmaxf(mm, red_f[w]);
    bcast_max = mm;
  }
  __syncthreads();
  const float rowmax = bcast_max;

  double e  = active ? exp((double)v - (double)rowmax) : 0.0;
  double sp = active ? (double)v : 0.0;
  double es = wave_sum_d(e);
  double ss = wave_sum_d(sp);
  if (lane == 0) { red_d[wid] = es; red_d[8 + wid] = ss; }
  __syncthreads();
  if (tid == 0) {
    double esum = 0.0, ssum = 0.0;
    int rank = 0, mcnt = 0;
    #pragma unroll
    for (int w = 0; w < NTHR / 64; ++w) {
      esum += red_d[w]; ssum += red_d[8 + w];
      rank += red_i[w]; mcnt += red_i[8 + w];
    }
    const double S    = ssum - (double)DA * ((double)rowmax + log(esum));
    const double coef = (double)(2 * rank - mcnt + 1);
    dev_store_d(&T[row], coef * S);     // 8 B scoped publish
    dev_store_i(&RK[row], rank);        // 4 B scoped publish
  }

  asm volatile("s_waitcnt vmcnt(0)" ::: "memory");   // publishes at LLC
  __syncthreads();
  if (tid == 0)
    ticket_sh = __hip_atomic_fetch_add(ticket, 1, __ATOMIC_RELAXED,
                                       __HIP_MEMORY_SCOPE_AGENT);
  __syncthreads();
  if (ticket_sh != B - 1) return;       // not the last row block
  asm volatile("" ::: "memory");        // don't hoist loads above ticket

  // ---- tail (winner block): sum 512 doubles + 512 ints, write loss ----
  double tloc = 0.0;
  int    rloc = 0;
  for (int i = tid; i < B; i += NTHR) { // fixed per-thread order: i, i+320
    tloc += dev_load_d(&T[i]);
    rloc += dev_load_i(&RK[i]);
  }
  #pragma unroll
  for (int off = 32; off >= 1; off >>= 1) {
    tloc += __shfl_down(tloc, off);
    rloc += __shfl_down(rloc, off);
  }
  if (lane == 0) { red_d[wid] = tloc; red_i[wid] = rloc; }
  __syncthreads();
  if (tid == 0) {
    double ts = 0.0; int rs = 0;
    #pragma unroll
    for (int w = 0; w < NTHR / 64; ++w) { ts += red_d[w]; rs += red_i[w]; }
    out[0] = (float)((rs > 0) ? ts / (double)rs : ts);
  }
}

// ---------------------------------------------------------------------------
// Fallback 3-kernel path (proven, for tiny workspace): ksplit=2.
// ---------------------------------------------------------------------------
template <int KCF>
__global__ __launch_bounds__(NTHR) void gemm_partial_fb(
    const float* __restrict__ x_f, const float* __restrict__ W,
    float* __restrict__ part) {
  const int c = threadIdx.x, rg = blockIdx.x, ks = blockIdx.y;
  const int row0 = rg * RT, k0 = ks * KCF, ksplit = DF / KCF;
  if (c >= DA) return;
  float acc[RT];
  #pragma unroll
  for (int r = 0; r < RT; ++r) acc[r] = 0.f;
  const float* Wp = W + (size_t)k0 * DA + c;
  const float* xp = x_f + (size_t)row0 * DF + k0;
  for (int k = 0; k < KCF; k += 8) {
    float w[8];
    #pragma unroll
    for (int j = 0; j < 8; ++j) w[j] = Wp[(size_t)(k + j) * DA];
    #pragma unroll
    for (int r = 0; r < RT; ++r) {
      const float* xr = xp + (size_t)r * DF + k;
      #pragma unroll
      for (int j = 0; j < 8; ++j) acc[r] = fmaf(xr[j], w[j], acc[r]);
    }
  }
  float* pp = part + ((size_t)(rg * ksplit + ks) * RT) * DA + c;
  #pragma unroll
  for (int r = 0; r < RT; ++r) pp[(size_t)r * DA] = acc[r];
}

template <int KS>
__global__ __launch_bounds__(NTHR) void row_stats_fb(
    const float* __restrict__ part, const float* __restrict__ b,
    double* __restrict__ S) {
  __shared__ float  red_f[8];
  __shared__ double red_d[16];
  __shared__ float  bcast_max;
  const int tid = threadIdx.x, wid = tid >> 6, lane = tid & 63;
  const int row = blockIdx.x, rg = row / RT, r = row & (RT - 1);
  float v = -INFINITY;
  if (tid < DA) {
    const float* pb = part + ((size_t)(rg * KS) * RT + r) * DA + tid;
    float ps[KS];
    #pragma unroll
    for (int p = 0; p < KS; ++p) ps[p] = pb[(size_t)p * RT * DA];
    float sv = b[tid];
    #pragma unroll
    for (int p = 0; p < KS; ++p) sv += ps[p];
    v = sv;
  }
  float m = wave_max_f(v);
  if (lane == 0) red_f[wid] = m;
  __syncthreads();
  if (tid == 0) {
    float mm = red_f[0];
    #pragma unroll
    for (int w = 1; w < NTHR / 64; ++w) mm = fmaxf(mm, red_f[w]);
    bcast_max = mm;
  }
  __syncthreads();
  const float rowmax = bcast_max;
  double e  = (tid < DA) ? exp((double)v - (double)rowmax) : 0.0;
  double sp = (tid < DA) ? (double)v : 0.0;
  double es = wave_sum_d(e);
  double ss = wave_sum_d(sp);
  if (lane == 0) { red_d[wid] = es; red_d[8 + wid] = ss; }
  __syncthreads();
  if (tid == 0) {
    double esum = 0.0, ssum = 0.0;
    #pragma unroll
    for (int w = 0; w < NTHR / 64; ++w) { esum += red_d[w]; ssum += red_d[8 + w]; }
    S[row] = ssum - (double)DA * ((double)rowmax + log(esum));
  }
}

__global__ __launch_bounds__(1024) void pair_reduce_fb(
    const double* __restrict__ S, const int* __restrict__ labels,
    float* __restrict__ out) {
  __shared__ double    Ss[B];
  __shared__ int       Ls[B];
  __shared__ double    red_d[16];
  __shared__ long long red_i[16];
  const int tid = threadIdx.x;
  if (tid < B) { Ss[tid] = S[tid]; Ls[tid] = labels[tid]; }
  __syncthreads();
  double lsum = 0.0;
  long long lcnt = 0;
  for (int p = tid; p < B * B; p += 1024) {
    int i = p >> 9, j = p & (B - 1);
    if (j > i && Ls[i] == Ls[j]) { lsum += Ss[j] - Ss[i]; lcnt++; }
  }
  #pragma unroll
  for (int off = 32; off >= 1; off >>= 1) {
    lsum += __shfl_down(lsum, off);
    lcnt += __shfl_down(lcnt, off);
  }
  const int wid = tid >> 6, lane = tid & 63;
  if (lane == 0) { red_d[wid] = lsum; red_i[wid] = lcnt; }
  __syncthreads();
  if (tid == 0) {
    double s = 0.0; long long c = 0;
    #pragma unroll
    for (int w = 0; w < 16; ++w) { s += red_d[w]; c += red_i[w]; }
    out[0] = (float)((c > 0) ? s / (double)c : s);
  }
}

// ---------------------------------------------------------------------------
extern "C" void kernel_launch(void* const* d_in, const int* in_sizes, int n_in,
                              void* d_out, int out_size, void* d_ws, size_t ws_size,
                              hipStream_t stream) {
  const float* x_f    = (const float*)d_in[0];   // [B, DF]
  const float* W      = (const float*)d_in[1];   // [DF, DA]
  const float* b      = (const float*)d_in[2];   // [DA]
  // d_in[3] = seen_att: cancels exactly for same-label pairs (unused)
  const int*   labels = (const int*)d_in[4];     // [B]

  // ws layout: [ticket @0][T: 512 doubles @4096][RK: 512 ints @8192]
  //            [part @16384: KSPLIT*B*DA floats (~10.2 MB)]
  const size_t need = 16384 + (size_t)KSPLIT * B * DA * 4;
  if (ws_size >= need) {
    int*    ticket = (int*)d_ws;
    double* T      = (double*)((char*)d_ws + 4096);
    int*    RK     = (int*)((char*)d_ws + 8192);
    float*  part   = (float*)((char*)d_ws + 16384);
    dim3 g1(NRG, KSPLIT);                         // 64 x 16 = 1024 blocks
    gemm_partial_kernel<DF / KSPLIT><<<g1, NTHR, 0, stream>>>(x_f, W, part,
                                                              ticket);
    rowstats_pair_kernel<KSPLIT><<<B, NTHR, 0, stream>>>(
        part, b, labels, T, RK, ticket, (float*)d_out);
  } else {                                       // tiny-ws fallback (proven)
    double* S    = (double*)d_ws;
    float*  part = (float*)((char*)d_ws + 4096);
    dim3 g1(B / RT, 2);
    gemm_partial_fb<DF / 2><<<g1, NTHR, 0, stream>>>(x_f, W, part);
    row_stats_fb<2><<<B, NTHR, 0, stream>>>(part, b, S);
    pair_reduce_fb<<<1, 1024, 0, stream>>>(S, labels, (float*)d_out);
  }
}